// Round 2
// baseline (34.707 us; speedup 1.0000x reference)
//
#include <hip/hip_runtime.h>

#define THREADS 256
#define CPT 2  // coords per thread

// ---------------------------------------------------------------------------
// Prep kernel: one block, 256 threads. Computes per-particle constants at
// time_idx, drops particles with exactly-zero weight (time_mask==0 etc.),
// compacts them with a deterministic prefix sum into d_ws as pairs of float4:
//   pa = {px, py, pz, -log2(e)/(2 r^2)}
//   pb = {A*dx, A*dy, A*dz, 9 r^2}        A = w / (r^3 * 40000)
// so the inner loop is:
//   each = exp2(d2*pa.w) * rsq(d2) * cross(loc, pb.xyz)   if d2 < pb.w
// ---------------------------------------------------------------------------
__global__ void vortex_prep(const float* __restrict__ ppos,
                            const float* __restrict__ pdir,
                            const float* __restrict__ pint,
                            const float* __restrict__ iraw,
                            const float* __restrict__ rad,
                            const int*   __restrict__ tmask,
                            const int*   __restrict__ tidxp,
                            int P, int T,
                            float4* __restrict__ parts,
                            int*    __restrict__ dcount) {
    __shared__ int flags[THREADS];
    const int p = threadIdx.x;
    const int t = *tidxp;

    bool active = false;
    float4 a = make_float4(0.f, 0.f, 0.f, 0.f);
    float4 b = make_float4(0.f, 0.f, 0.f, 0.f);

    if (p < P) {
        float m   = (float)tmask[p * T + t];
        float cl  = fminf(fmaxf(iraw[p], 0.0f), 10.0f);
        float w   = sqrtf(cl + 1e-8f) * pint[p * T + t] * m;
        float r   = fmaxf(0.2f * (0.5f * rad[p] + 1.0f), 0.0f);
        active    = (w != 0.0f) && (r > 0.0f);
        if (active) {
            const float* pp = ppos + (size_t)(p * T + t) * 3;
            const float* pd = pdir + (size_t)(p * T + t) * 3;
            float A = w / (r * r * r * 40000.0f);
            a.x = pp[0]; a.y = pp[1]; a.z = pp[2];
            a.w = -1.442695040888963f / (2.0f * r * r);   // -log2(e)/(2r^2)
            b.x = A * pd[0]; b.y = A * pd[1]; b.z = A * pd[2];
            b.w = 9.0f * r * r;
        }
    }
    flags[p] = active ? 1 : 0;
    __syncthreads();

    // deterministic (stable-order) compaction via serial prefix scan —
    // trivial one-time cost, keeps summation order run-to-run identical
    int pre = 0, tot = 0;
    for (int i = 0; i < THREADS; ++i) {
        int f = flags[i];
        pre += (i < p) ? f : 0;
        tot += f;
    }
    if (active) {
        parts[2 * pre]     = a;
        parts[2 * pre + 1] = b;
    }
    if (p == 0) *dcount = tot;
}

// ---------------------------------------------------------------------------
// Main kernel: each thread owns CPT coords (stride-THREADS within the block's
// chunk for coalescing) and loops over the compacted particle list staged in
// LDS (uniform-address broadcast reads).
// ---------------------------------------------------------------------------
__global__ __launch_bounds__(THREADS) void vortex_main(
        const float*  __restrict__ coord,
        const float4* __restrict__ parts,
        const int*    __restrict__ dcount,
        float*        __restrict__ out,
        int N) {
    __shared__ float4 sp[2 * THREADS];

    const int cnt = *dcount;                       // uniform
    for (int i = threadIdx.x; i < 2 * cnt; i += THREADS) sp[i] = parts[i];
    __syncthreads();

    const int i0 = blockIdx.x * (THREADS * CPT) + threadIdx.x;
    const int i1 = i0 + THREADS;
    const bool v0 = (i0 < N), v1 = (i1 < N);

    float cx0 = 0.f, cy0 = 0.f, cz0 = 0.f;
    float cx1 = 0.f, cy1 = 0.f, cz1 = 0.f;
    if (v0) { cx0 = coord[3 * i0]; cy0 = coord[3 * i0 + 1]; cz0 = coord[3 * i0 + 2]; }
    if (v1) { cx1 = coord[3 * i1]; cy1 = coord[3 * i1 + 1]; cz1 = coord[3 * i1 + 2]; }

    float ax0 = 0.f, ay0 = 0.f, az0 = 0.f;
    float ax1 = 0.f, ay1 = 0.f, az1 = 0.f;

    #pragma unroll 4
    for (int p = 0; p < cnt; ++p) {
        const float4 pa = sp[2 * p];
        const float4 pb = sp[2 * p + 1];
        {   // coord 0
            float lx = pa.x - cx0, ly = pa.y - cy0, lz = pa.z - cz0;
            float d2 = fmaf(lx, lx, fmaf(ly, ly, lz * lz));
            float s  = __builtin_amdgcn_exp2f(d2 * pa.w) * __builtin_amdgcn_rsqf(d2);
            s = (d2 < pb.w) ? s : 0.0f;
            float crx = fmaf(ly, pb.z, -(lz * pb.y));
            float cry = fmaf(lz, pb.x, -(lx * pb.z));
            float crz = fmaf(lx, pb.y, -(ly * pb.x));
            ax0 = fmaf(s, crx, ax0);
            ay0 = fmaf(s, cry, ay0);
            az0 = fmaf(s, crz, az0);
        }
        {   // coord 1
            float lx = pa.x - cx1, ly = pa.y - cy1, lz = pa.z - cz1;
            float d2 = fmaf(lx, lx, fmaf(ly, ly, lz * lz));
            float s  = __builtin_amdgcn_exp2f(d2 * pa.w) * __builtin_amdgcn_rsqf(d2);
            s = (d2 < pb.w) ? s : 0.0f;
            float crx = fmaf(ly, pb.z, -(lz * pb.y));
            float cry = fmaf(lz, pb.x, -(lx * pb.z));
            float crz = fmaf(lx, pb.y, -(ly * pb.x));
            ax1 = fmaf(s, crx, ax1);
            ay1 = fmaf(s, cry, ay1);
            az1 = fmaf(s, crz, az1);
        }
    }

    if (v0) { out[3 * i0] = ax0; out[3 * i0 + 1] = ay0; out[3 * i0 + 2] = az0; }
    if (v1) { out[3 * i1] = ax1; out[3 * i1 + 1] = ay1; out[3 * i1 + 2] = az1; }
}

extern "C" void kernel_launch(void* const* d_in, const int* in_sizes, int n_in,
                              void* d_out, int out_size, void* d_ws, size_t ws_size,
                              hipStream_t stream) {
    const float* coord = (const float*)d_in[0];
    const float* ppos  = (const float*)d_in[1];
    const float* pdir  = (const float*)d_in[2];
    const float* pint  = (const float*)d_in[3];
    const float* iraw  = (const float*)d_in[4];
    const float* rad   = (const float*)d_in[5];
    const int*   tmask = (const int*)d_in[6];
    const int*   tidx  = (const int*)d_in[7];
    float* out = (float*)d_out;

    const int N = in_sizes[0] / 3;        // 262144 coords
    const int P = in_sizes[4];            // 256 particles (intensity_raw is (P,1))
    const int T = in_sizes[3] / P;        // 8 time steps (particle_intensity is (P,T,1))

    float4* parts = (float4*)d_ws;
    int* dcount   = (int*)((char*)d_ws + (size_t)2 * THREADS * sizeof(float4));

    hipLaunchKernelGGL(vortex_prep, dim3(1), dim3(THREADS), 0, stream,
                       ppos, pdir, pint, iraw, rad, tmask, tidx, P, T, parts, dcount);

    const int coordsPerBlock = THREADS * CPT;
    const int blocks = (N + coordsPerBlock - 1) / coordsPerBlock;
    hipLaunchKernelGGL(vortex_main, dim3(blocks), dim3(THREADS), 0, stream,
                       coord, parts, dcount, out, N);
}

// Round 3
// 30.883 us; speedup vs baseline: 1.1238x; 1.1238x over previous
//
#include <hip/hip_runtime.h>

#define THREADS 256   // 4 waves/block
#define NPMAX   256   // max particles

// ---------------------------------------------------------------------------
// Single fused kernel. Each block:
//   1) redundantly computes per-particle constants at time_idx (cheap, L2-hit
//      after the first blocks) and compacts active particles into LDS with a
//      wave-ballot prefix scan (deterministic, stable order),
//   2) each thread owns ONE coord and loops over the compacted particle list
//      (uniform-address LDS broadcast reads).
// Per-particle constants, as two float4:
//   pa = {px, py, pz, -log2(e)/(2 r^2)}
//   pb = {A*dx, A*dy, A*dz, 9 r^2}        A = w / (r^3 * 40000)
// inner loop:  each = exp2(d2*pa.w) * rsq(d2) * cross(loc, pb.xyz)  if d2<pb.w
// ---------------------------------------------------------------------------
__global__ __launch_bounds__(THREADS) void vortex_fused(
        const float* __restrict__ coord,
        const float* __restrict__ ppos,
        const float* __restrict__ pdir,
        const float* __restrict__ pint,
        const float* __restrict__ iraw,
        const float* __restrict__ rad,
        const int*   __restrict__ tmask,
        const int*   __restrict__ tidxp,
        float*       __restrict__ out,
        int N, int P, int T) {
    __shared__ float4 sp[2 * NPMAX];
    __shared__ int    wtot[THREADS / 64];
    __shared__ int    s_cnt;

    const int tid  = threadIdx.x;
    const int lane = tid & 63;
    const int wid  = tid >> 6;

    // ---- coord load first so it overlaps the prep work ----
    const int i0 = blockIdx.x * THREADS + tid;
    const bool v0 = (i0 < N);
    float cx = 0.f, cy = 0.f, cz = 0.f;
    if (v0) { cx = coord[3 * i0]; cy = coord[3 * i0 + 1]; cz = coord[3 * i0 + 2]; }

    // ---- per-particle prep + ballot compaction ----
    const int t = *tidxp;
    bool active = false;
    float4 a, b;
    if (tid < P) {
        const int p = tid;
        float m  = (float)tmask[p * T + t];
        float cl = fminf(fmaxf(iraw[p], 0.0f), 10.0f);
        float w  = sqrtf(cl + 1e-8f) * pint[p * T + t] * m;
        float r  = fmaxf(0.2f * (0.5f * rad[p] + 1.0f), 0.0f);
        active   = (w != 0.0f) && (r > 0.0f);
        if (active) {
            const float* pp = ppos + (size_t)(p * T + t) * 3;
            const float* pd = pdir + (size_t)(p * T + t) * 3;
            float A = w / (r * r * r * 40000.0f);
            a = make_float4(pp[0], pp[1], pp[2], -1.442695040888963f / (2.0f * r * r));
            b = make_float4(A * pd[0], A * pd[1], A * pd[2], 9.0f * r * r);
        }
    }
    unsigned long long bm = __ballot(active);
    int pre  = __popcll(bm & ((1ull << lane) - 1ull));
    if (lane == 0) wtot[wid] = __popcll(bm);
    __syncthreads();
    int off = 0, tot = 0;
    #pragma unroll
    for (int w2 = 0; w2 < THREADS / 64; ++w2) {
        int c = wtot[w2];
        if (w2 < wid) off += c;
        tot += c;
    }
    if (active) {
        int pos = off + pre;
        sp[2 * pos]     = a;
        sp[2 * pos + 1] = b;
    }
    if (tid == 0) s_cnt = tot;
    __syncthreads();
    const int cnt = s_cnt;   // uniform across block

    // ---- main interaction loop ----
    float ax = 0.f, ay = 0.f, az = 0.f;
    #pragma unroll 4
    for (int p = 0; p < cnt; ++p) {
        const float4 pa = sp[2 * p];
        const float4 pb = sp[2 * p + 1];
        float lx = pa.x - cx, ly = pa.y - cy, lz = pa.z - cz;
        float d2 = fmaf(lx, lx, fmaf(ly, ly, lz * lz));
        float s  = __builtin_amdgcn_exp2f(d2 * pa.w) * __builtin_amdgcn_rsqf(d2);
        s = (d2 < pb.w) ? s : 0.0f;
        float crx = fmaf(ly, pb.z, -(lz * pb.y));
        float cry = fmaf(lz, pb.x, -(lx * pb.z));
        float crz = fmaf(lx, pb.y, -(ly * pb.x));
        ax = fmaf(s, crx, ax);
        ay = fmaf(s, cry, ay);
        az = fmaf(s, crz, az);
    }

    if (v0) { out[3 * i0] = ax; out[3 * i0 + 1] = ay; out[3 * i0 + 2] = az; }
}

extern "C" void kernel_launch(void* const* d_in, const int* in_sizes, int n_in,
                              void* d_out, int out_size, void* d_ws, size_t ws_size,
                              hipStream_t stream) {
    const float* coord = (const float*)d_in[0];
    const float* ppos  = (const float*)d_in[1];
    const float* pdir  = (const float*)d_in[2];
    const float* pint  = (const float*)d_in[3];
    const float* iraw  = (const float*)d_in[4];
    const float* rad   = (const float*)d_in[5];
    const int*   tmask = (const int*)d_in[6];
    const int*   tidx  = (const int*)d_in[7];
    float* out = (float*)d_out;

    const int N = in_sizes[0] / 3;        // 262144 coords
    const int P = in_sizes[4];            // 256 particles (intensity_raw is (P,1))
    const int T = in_sizes[3] / P;        // 8 time steps (particle_intensity is (P,T,1))

    const int blocks = (N + THREADS - 1) / THREADS;
    hipLaunchKernelGGL(vortex_fused, dim3(blocks), dim3(THREADS), 0, stream,
                       coord, ppos, pdir, pint, iraw, rad, tmask, tidx, out, N, P, T);
}

// Round 4
// 29.169 us; speedup vs baseline: 1.1899x; 1.0587x over previous
//
#include <hip/hip_runtime.h>

#define THREADS 256   // 4 waves/block
#define CPT     2     // coords per thread -> 512 blocks, 2 blocks/CU
#define NPMAX   256   // max particles

// ---------------------------------------------------------------------------
// Single fused kernel. Each block:
//   1) redundantly computes per-particle constants at time_idx and compacts
//      active particles into LDS with a wave-ballot prefix scan
//      (deterministic, stable order),
//   2) each thread owns CPT coords and loops over the compacted particle
//      list (uniform-address LDS broadcast reads, amortized over CPT coords).
// Per-particle constants, as two float4:
//   pa = {px, py, pz, -log2(e)/(2 r^2)}
//   pb = {A*dx, A*dy, A*dz, 9 r^2}        A = w / (r^3 * 40000)
// inner loop:  each = exp2(d2*pa.w) * rsq(d2) * cross(loc, pb.xyz)  if d2<pb.w
// ---------------------------------------------------------------------------
__global__ __launch_bounds__(THREADS) void vortex_fused(
        const float* __restrict__ coord,
        const float* __restrict__ ppos,
        const float* __restrict__ pdir,
        const float* __restrict__ pint,
        const float* __restrict__ iraw,
        const float* __restrict__ rad,
        const int*   __restrict__ tmask,
        const int*   __restrict__ tidxp,
        float*       __restrict__ out,
        int N, int P, int T) {
    __shared__ float4 sp[2 * NPMAX];
    __shared__ int    wtot[THREADS / 64];
    __shared__ int    s_cnt;

    const int tid  = threadIdx.x;
    const int lane = tid & 63;
    const int wid  = tid >> 6;

    // ---- coord loads first so they overlap the prep work ----
    const int i0 = blockIdx.x * (THREADS * CPT) + tid;
    const int i1 = i0 + THREADS;
    const bool v0 = (i0 < N), v1 = (i1 < N);
    float cx0 = 0.f, cy0 = 0.f, cz0 = 0.f;
    float cx1 = 0.f, cy1 = 0.f, cz1 = 0.f;
    if (v0) { cx0 = coord[3 * i0]; cy0 = coord[3 * i0 + 1]; cz0 = coord[3 * i0 + 2]; }
    if (v1) { cx1 = coord[3 * i1]; cy1 = coord[3 * i1 + 1]; cz1 = coord[3 * i1 + 2]; }

    // ---- per-particle prep + ballot compaction ----
    const int t = *tidxp;
    bool active = false;
    float4 a, b;
    if (tid < P) {
        const int p = tid;
        float m  = (float)tmask[p * T + t];
        float cl = fminf(fmaxf(iraw[p], 0.0f), 10.0f);
        float w  = sqrtf(cl + 1e-8f) * pint[p * T + t] * m;
        float r  = fmaxf(0.2f * (0.5f * rad[p] + 1.0f), 0.0f);
        active   = (w != 0.0f) && (r > 0.0f);
        if (active) {
            const float* pp = ppos + (size_t)(p * T + t) * 3;
            const float* pd = pdir + (size_t)(p * T + t) * 3;
            float A = w / (r * r * r * 40000.0f);
            a = make_float4(pp[0], pp[1], pp[2], -1.442695040888963f / (2.0f * r * r));
            b = make_float4(A * pd[0], A * pd[1], A * pd[2], 9.0f * r * r);
        }
    }
    unsigned long long bm = __ballot(active);
    int pre = __popcll(bm & ((1ull << lane) - 1ull));
    if (lane == 0) wtot[wid] = __popcll(bm);
    __syncthreads();
    int off = 0, tot = 0;
    #pragma unroll
    for (int w2 = 0; w2 < THREADS / 64; ++w2) {
        int c = wtot[w2];
        if (w2 < wid) off += c;
        tot += c;
    }
    if (active) {
        int pos = off + pre;
        sp[2 * pos]     = a;
        sp[2 * pos + 1] = b;
    }
    if (tid == 0) s_cnt = tot;
    __syncthreads();
    const int cnt = s_cnt;   // uniform across block

    // ---- main interaction loop: 2 LDS reads serve CPT=2 coords ----
    float ax0 = 0.f, ay0 = 0.f, az0 = 0.f;
    float ax1 = 0.f, ay1 = 0.f, az1 = 0.f;
    #pragma unroll 4
    for (int p = 0; p < cnt; ++p) {
        const float4 pa = sp[2 * p];
        const float4 pb = sp[2 * p + 1];
        {   // coord 0
            float lx = pa.x - cx0, ly = pa.y - cy0, lz = pa.z - cz0;
            float d2 = fmaf(lx, lx, fmaf(ly, ly, lz * lz));
            float s  = __builtin_amdgcn_exp2f(d2 * pa.w) * __builtin_amdgcn_rsqf(d2);
            s = (d2 < pb.w) ? s : 0.0f;
            float crx = fmaf(ly, pb.z, -(lz * pb.y));
            float cry = fmaf(lz, pb.x, -(lx * pb.z));
            float crz = fmaf(lx, pb.y, -(ly * pb.x));
            ax0 = fmaf(s, crx, ax0);
            ay0 = fmaf(s, cry, ay0);
            az0 = fmaf(s, crz, az0);
        }
        {   // coord 1
            float lx = pa.x - cx1, ly = pa.y - cy1, lz = pa.z - cz1;
            float d2 = fmaf(lx, lx, fmaf(ly, ly, lz * lz));
            float s  = __builtin_amdgcn_exp2f(d2 * pa.w) * __builtin_amdgcn_rsqf(d2);
            s = (d2 < pb.w) ? s : 0.0f;
            float crx = fmaf(ly, pb.z, -(lz * pb.y));
            float cry = fmaf(lz, pb.x, -(lx * pb.z));
            float crz = fmaf(lx, pb.y, -(ly * pb.x));
            ax1 = fmaf(s, crx, ax1);
            ay1 = fmaf(s, cry, ay1);
            az1 = fmaf(s, crz, az1);
        }
    }

    if (v0) { out[3 * i0] = ax0; out[3 * i0 + 1] = ay0; out[3 * i0 + 2] = az0; }
    if (v1) { out[3 * i1] = ax1; out[3 * i1 + 1] = ay1; out[3 * i1 + 2] = az1; }
}

extern "C" void kernel_launch(void* const* d_in, const int* in_sizes, int n_in,
                              void* d_out, int out_size, void* d_ws, size_t ws_size,
                              hipStream_t stream) {
    const float* coord = (const float*)d_in[0];
    const float* ppos  = (const float*)d_in[1];
    const float* pdir  = (const float*)d_in[2];
    const float* pint  = (const float*)d_in[3];
    const float* iraw  = (const float*)d_in[4];
    const float* rad   = (const float*)d_in[5];
    const int*   tmask = (const int*)d_in[6];
    const int*   tidx  = (const int*)d_in[7];
    float* out = (float*)d_out;

    const int N = in_sizes[0] / 3;        // 262144 coords
    const int P = in_sizes[4];            // 256 particles (intensity_raw is (P,1))
    const int T = in_sizes[3] / P;        // 8 time steps (particle_intensity is (P,T,1))

    const int coordsPerBlock = THREADS * CPT;
    const int blocks = (N + coordsPerBlock - 1) / coordsPerBlock;
    hipLaunchKernelGGL(vortex_fused, dim3(blocks), dim3(THREADS), 0, stream,
                       coord, ppos, pdir, pint, iraw, rad, tmask, tidx, out, N, P, T);
}